// Round 11
// baseline (200.610 us; speedup 1.0000x reference)
//
#include <hip/hip_runtime.h>
#include <stdint.h>

// InstanceHead on MI355X — f32/int32 inputs, f32 OUTPUT buffer.
// N=100000, M=256, B=8, L=128, D=64.
// R16: R14 semantics (best, 70us) with the CODE IMAGE shrunk ~3x.
// Evidence: R15's online softmax regressed (serial m-chain + VGPR);
// across R7-R15 wave lifetime is ~10x the computed critical path while
// EVERY pipe counter reads idle — the one untested suspect is instruction
// fetch: fully-unrolled ~17KB straight-line kernels stream through L1I
// once per wave, thrashed by resident blocks at different phases.  R16:
//   - pass1/pass2 rolled at #pragma unroll 4 (DS loads still batch 16/body)
//   - e packed f16x2 staged in LDS e_s[4][16][64] (rolled loops need a
//     runtime mt index; same-wave DS ordering, no barrier)
//   - epilogue rolled (#pragma unroll 2) with ping-pong cen prefetch;
//     group-0 burst issued before pass1 (flies across both passes)
// Keeps R14: batched ff/wbv preloads, transposed GEMM2 (mfma(cen,clu)),
// dwordx4 stores, geometric batch fold (x+=4096*b; cross-batch exp ->
// exact 0; gate d2m<4e6), cmeta LDS-staged, wave-private clu_s transpose,
// __launch_bounds__(256,3).

#define NN 100000
#define MM 256
#define LL 128
#define DD 64
#define NTILES (NN / 16)  // 6250, exact

typedef float f32x4 __attribute__((ext_vector_type(4)));
typedef __bf16 bf16x8 __attribute__((ext_vector_type(8)));
typedef __fp16 fp16x2 __attribute__((ext_vector_type(2)));

union U16x8 { uint4 u; bf16x8 v; unsigned short s[8]; };
union UH2 { unsigned int u; fp16x2 h; };

static __device__ __forceinline__ unsigned short f2bf(float f) {
  union { float f; unsigned int i; } t; t.f = f;
  unsigned int x = t.i;
  x += 0x7fffu + ((x >> 16) & 1u);  // round-to-nearest-even
  return (unsigned short)(x >> 16);
}

// ---------------- prep: cen (bf16), W^T (bf16), centroid meta ----------------
__global__ __launch_bounds__(256) void prep_kernel(
    const int* __restrict__ cen_coords,
    const float* __restrict__ cen_feats,
    const float* __restrict__ conf,
    const float* __restrict__ W,
    const float* __restrict__ bvec,
    unsigned short* __restrict__ cen_ws,   // [256][64] bf16
    unsigned short* __restrict__ wt_ws,    // [64][128] bf16 (W transposed)
    float4* __restrict__ cmeta_ws)         // [256] {x+4096*batch, y, z, 0}
{
  int tid = threadIdx.x;
  if (blockIdx.x < 16) {
    int m = blockIdx.x * 16 + (tid >> 4);
    int c = tid & 15;
    float a0 = 0.f, a1 = 0.f, a2 = 0.f, a3 = 0.f;
    for (int l = 0; l < LL; l++) {
      float f = cen_feats[m * LL + l];
      const float* wr = W + l * DD + c;
      a0 += f * wr[0];  a1 += f * wr[16];
      a2 += f * wr[32]; a3 += f * wr[48];
    }
    float cf = conf[m];
    cen_ws[m * DD + c +  0] = f2bf(cf * (a0 + bvec[c +  0]));
    cen_ws[m * DD + c + 16] = f2bf(cf * (a1 + bvec[c + 16]));
    cen_ws[m * DD + c + 32] = f2bf(cf * (a2 + bvec[c + 32]));
    cen_ws[m * DD + c + 48] = f2bf(cf * (a3 + bvec[c + 48]));
  } else {
    for (int i = tid; i < LL * DD; i += 256) {
      int l = i >> 6, d = i & 63;
      wt_ws[d * LL + l] = f2bf(W[l * DD + d]);
    }
    {
      int4 cc = ((const int4*)cen_coords)[tid];  // {batch, x, y, z}
      float4 f;
      f.x = (float)cc.y + 4096.0f * (float)cc.x;  // batch folded into x
      f.y = (float)cc.z;
      f.z = (float)cc.w;
      f.w = 0.0f;
      cmeta_ws[tid] = f;
    }
  }
}

// ---------------- main: fused, 1 wave/tile, rolled-loop version ----------------
__global__ __launch_bounds__(256, 3) void main_kernel(
    const int4* __restrict__ clu_coords4,
    const float* __restrict__ feats,
    const float* __restrict__ bvec,
    const unsigned short* __restrict__ cen_ws,
    const unsigned short* __restrict__ wt_ws,
    const float4* __restrict__ cmeta,
    float* __restrict__ out)
{
  __shared__ __align__(16) unsigned short clu_s[4][16 * 72];  // 9216 B
  __shared__ __align__(16) float4 cmeta_s[MM];                // 4096 B
  __shared__ __align__(16) uint2 e_s[4][16][64];              // 32768 B

  int tid = threadIdx.x;
  cmeta_s[tid] = cmeta[tid];   // stage once per block
  __syncthreads();             // before any divergent exit

  int wave = tid >> 6, lane = tid & 63;
  int q = lane >> 4, c = lane & 15;
  int tile = blockIdx.x * 4 + wave;
  if (tile >= NTILES) return;

  // ---- batched long-latency loads: feats (8x dwordx4), W frags (16x dwordx4),
  //      row coord — ALL issued before any dependent compute.
  const float4* fb = (const float4*)(feats + (size_t)(tile * 16 + c) * LL);
  float4 ff[8];
#pragma unroll
  for (int ks = 0; ks < 4; ks++) {
    ff[2 * ks]     = fb[ks * 8 + q * 2];
    ff[2 * ks + 1] = fb[ks * 8 + q * 2 + 1];
  }
  const uint4* wb = (const uint4*)wt_ws;
  uint4 wbv[16];
#pragma unroll
  for (int ks = 0; ks < 4; ks++)
#pragma unroll
    for (int nt = 0; nt < 4; nt++)
      wbv[ks * 4 + nt] = wb[(nt * 16 + c) * 16 + ks * 4 + q];
  int4 rm = clu_coords4[tile * 16 + c];  // one row per lane (4-way broadcast)
  float rx = (float)rm.y + 4096.0f * (float)rm.x;  // batch folded, exact
  float ry = (float)rm.z;
  float rz = (float)rm.w;

  // ---- GEMM1: clu = feats @ W (+b)
  f32x4 acc[4] = {{0,0,0,0},{0,0,0,0},{0,0,0,0},{0,0,0,0}};
#pragma unroll
  for (int ks = 0; ks < 4; ks++) {
    float4 f0 = ff[2 * ks], f1 = ff[2 * ks + 1];
    U16x8 a;
    a.v[0] = (__bf16)f0.x; a.v[1] = (__bf16)f0.y; a.v[2] = (__bf16)f0.z; a.v[3] = (__bf16)f0.w;
    a.v[4] = (__bf16)f1.x; a.v[5] = (__bf16)f1.y; a.v[6] = (__bf16)f1.z; a.v[7] = (__bf16)f1.w;
#pragma unroll
    for (int nt = 0; nt < 4; nt++) {
      U16x8 b; b.u = wbv[ks * 4 + nt];
      acc[nt] = __builtin_amdgcn_mfma_f32_16x16x32_bf16(a.v, b.v, acc[nt], 0, 0, 0);
    }
  }
#pragma unroll
  for (int nt = 0; nt < 4; nt++) {
    float bv = bvec[nt * 16 + c];
    acc[nt][0] += bv; acc[nt][1] += bv; acc[nt][2] += bv; acc[nt][3] += bv;
  }
  // ---- row L2 norms (GEMM1 fragment rows q*4+r live across quad q's lanes)
  float inv_nrm[4];
#pragma unroll
  for (int r = 0; r < 4; r++) {
    float s = acc[0][r]*acc[0][r] + acc[1][r]*acc[1][r] + acc[2][r]*acc[2][r] + acc[3][r]*acc[3][r];
    s += __shfl_xor(s, 1); s += __shfl_xor(s, 2); s += __shfl_xor(s, 4); s += __shfl_xor(s, 8);
    inv_nrm[r] = 1.0f / fmaxf(sqrtf(s), 1e-12f);
  }
  // normalized clu -> LDS (bf16); inv_nrm applied HERE only
#pragma unroll
  for (int nt = 0; nt < 4; nt++)
#pragma unroll
    for (int r = 0; r < 4; r++) {
      union { __bf16 h; unsigned short s; } u;
      u.h = (__bf16)(acc[nt][r] * inv_nrm[r]);
      clu_s[wave][(q * 4 + r) * 72 + nt * 16 + c] = u.s;
    }

  // wave-private LDS transpose: DS pipe is in-order per wave, no barrier
  __builtin_amdgcn_sched_barrier(0);

  // ---- clu frags (B-operand of the swapped GEMM2): row c, k-slice q
  const uint4* cb = (const uint4*)(clu_s[wave]);
  U16x8 a0, a1;
  a0.u = cb[c * 9 + q];       // k = q*8 .. q*8+7
  a1.u = cb[c * 9 + 4 + q];   // k = 32+q*8 ..

  // ---- issue the group-0 epilogue cen burst now; the passes below are
  //      DS/VALU-only, so these 8 dwordx4 stay in flight across them.
  const uint4* cenb = (const uint4*)cen_ws;
  uint4 pb0[4], pb1[4];
#pragma unroll
  for (int j = 0; j < 4; j++) {
    pb0[j] = cenb[(j * 16 + c) * 8 + q];
    pb1[j] = cenb[(j * 16 + c) * 8 + 4 + q];
  }

  // ---- pass 1 (ROLLED x4): d^2 min for (row c, cols mt*16+q*4+r)
  float d2m = 1e30f;
  {
    const float4* cmp = &cmeta_s[q * 4];
#pragma unroll 4
    for (int mt = 0; mt < 16; mt++) {
      float4 cm0 = cmp[mt * 16 + 0];
      float4 cm1 = cmp[mt * 16 + 1];
      float4 cm2 = cmp[mt * 16 + 2];
      float4 cm3 = cmp[mt * 16 + 3];
      float dx, dy, dz;
      dx = rx - cm0.x; dy = ry - cm0.y; dz = rz - cm0.z;
      d2m = fminf(d2m, dx*dx + dy*dy + dz*dz);
      dx = rx - cm1.x; dy = ry - cm1.y; dz = rz - cm1.z;
      d2m = fminf(d2m, dx*dx + dy*dy + dz*dz);
      dx = rx - cm2.x; dy = ry - cm2.y; dz = rz - cm2.z;
      d2m = fminf(d2m, dx*dx + dy*dy + dz*dz);
      dx = rx - cm3.x; dy = ry - cm3.y; dz = rz - cm3.z;
      d2m = fminf(d2m, dx*dx + dy*dy + dz*dz);
    }
  }
  // reduce over the row's 4 lanes (same c, q=0..3 -> xor bits 4,5)
  d2m = fminf(d2m, __shfl_xor(d2m, 16));
  d2m = fminf(d2m, __shfl_xor(d2m, 32));
  float dmv = fmaxf(sqrtf(d2m), 0.1f);  // softmax reference (row min dist)

  // ---- pass 2 (ROLLED x4): e = exp(dmin - d); pack f16x2 -> LDS; row sum
  float rsum = 0.f;
  {
    const float4* cmp = &cmeta_s[q * 4];
#pragma unroll 4
    for (int mt = 0; mt < 16; mt++) {
      float4 cm0 = cmp[mt * 16 + 0];
      float4 cm1 = cmp[mt * 16 + 1];
      float4 cm2 = cmp[mt * 16 + 2];
      float4 cm3 = cmp[mt * 16 + 3];
      float dx, dy, dz;
      dx = rx - cm0.x; dy = ry - cm0.y; dz = rz - cm0.z;
      float d0 = fmaxf(sqrtf(dx*dx + dy*dy + dz*dz), 0.1f);
      dx = rx - cm1.x; dy = ry - cm1.y; dz = rz - cm1.z;
      float d1 = fmaxf(sqrtf(dx*dx + dy*dy + dz*dz), 0.1f);
      dx = rx - cm2.x; dy = ry - cm2.y; dz = rz - cm2.z;
      float d2 = fmaxf(sqrtf(dx*dx + dy*dy + dz*dz), 0.1f);
      dx = rx - cm3.x; dy = ry - cm3.y; dz = rz - cm3.z;
      float d3 = fmaxf(sqrtf(dx*dx + dy*dy + dz*dz), 0.1f);
      float e0 = __expf(dmv - d0);  // <= 1; cross-batch -> exact 0
      float e1 = __expf(dmv - d1);
      float e2 = __expf(dmv - d2);
      float e3 = __expf(dmv - d3);
      rsum += (e0 + e1) + (e2 + e3);
      UH2 p0, p1;
      p0.h = __builtin_amdgcn_cvt_pkrtz(e0, e1);
      p1.h = __builtin_amdgcn_cvt_pkrtz(e2, e3);
      e_s[wave][mt][lane] = make_uint2(p0.u, p1.u);
    }
  }
  rsum += __shfl_xor(rsum, 16);
  rsum += __shfl_xor(rsum, 32);
  // d2m >= 4e6 <=> no same-batch centroid -> exact-zero row
  float sc = (d2m < 4.0e6f) ? 1.0f / rsum : 0.f;

  // ---- epilogue (ROLLED x2): swapped GEMM2, ping-pong cen prefetch
  //      lane (c,q) reg r = out[row tile*16+c][col mt*16+q*4+r]
  float4* ob4 = (float4*)(out + (size_t)(tile * 16 + c) * MM) + q;
#pragma unroll 2
  for (int g = 0; g < 4; g++) {
    uint4 nb0[4], nb1[4];
    if (g < 3) {
#pragma unroll
      for (int j = 0; j < 4; j++) {
        nb0[j] = cenb[(((g + 1) * 4 + j) * 16 + c) * 8 + q];
        nb1[j] = cenb[(((g + 1) * 4 + j) * 16 + c) * 8 + 4 + q];
      }
    }
#pragma unroll
    for (int j = 0; j < 4; j++) {
      int mt = g * 4 + j;
      U16x8 b0, b1; b0.u = pb0[j]; b1.u = pb1[j];
      f32x4 dacc = {0, 0, 0, 0};
      dacc = __builtin_amdgcn_mfma_f32_16x16x32_bf16(b0.v, a0.v, dacc, 0, 0, 0);  // SWAPPED
      dacc = __builtin_amdgcn_mfma_f32_16x16x32_bf16(b1.v, a1.v, dacc, 0, 0, 0);
      uint2 ue = e_s[wave][mt][lane];
      UH2 p0, p1; p0.u = ue.x; p1.u = ue.y;
      float4 v;
      v.x = dacc[0] * ((float)p0.h[0] * sc);
      v.y = dacc[1] * ((float)p0.h[1] * sc);
      v.z = dacc[2] * ((float)p1.h[0] * sc);
      v.w = dacc[3] * ((float)p1.h[1] * sc);
      ob4[mt * 4] = v;
    }
    if (g < 3) {
#pragma unroll
      for (int j = 0; j < 4; j++) { pb0[j] = nb0[j]; pb1[j] = nb1[j]; }
    }
  }
}

extern "C" void kernel_launch(void* const* d_in, const int* in_sizes, int n_in,
                              void* d_out, int out_size, void* d_ws, size_t ws_size,
                              hipStream_t stream) {
  const int* clu_coords = (const int*)d_in[0];
  const int* cen_coords = (const int*)d_in[1];
  const float* clu_feats = (const float*)d_in[2];
  const float* cen_feats = (const float*)d_in[3];
  const float* conf      = (const float*)d_in[4];
  const float* W         = (const float*)d_in[5];
  const float* bvec      = (const float*)d_in[6];
  float* out = (float*)d_out;

  char* ws = (char*)d_ws;
  unsigned short* cen_ws = (unsigned short*)ws;              // 32768 B
  unsigned short* wt_ws  = (unsigned short*)(ws + 32768);    // 16384 B
  float4* cmeta_ws       = (float4*)(ws + 32768 + 16384);    // 4096 B

  prep_kernel<<<17, 256, 0, stream>>>(cen_coords, cen_feats, conf, W, bvec,
                                      cen_ws, wt_ws, cmeta_ws);
  main_kernel<<<(NTILES + 3) / 4, 256, 0, stream>>>(
      (const int4*)clu_coords, clu_feats, bvec, cen_ws, wt_ws, cmeta_ws, out);
}

// Round 13
// 183.695 us; speedup vs baseline: 1.0921x; 1.0921x over previous
//
#include <hip/hip_runtime.h>
#include <stdint.h>

// InstanceHead on MI355X — f32/int32 inputs, f32 OUTPUT buffer.
// N=100000, M=256, B=8, L=128, D=64.
// R18: R14 base (best, 70us) + the derivation-verified pieces of R17:
//  1. GEMM1 OPERAND SWAP: mfma(wt,ff) -> lane (c,q) reg r =
//     clu[c][nt*16+q*4+r] (row-major-in-lane).  LDS transpose becomes
//     4x ds_write_b64 (v_cvt_pk_bf16_f32 pairs) instead of 16x b16;
//     norm reduce = 2 shuffles (was 16); bias via float4.  READ side
//     (cb[c*9+q]) byte-identical to R14's proven path.
//     (R17's in-register transpose is abandoned: its source-side select
//     is provably impossible — each source lane serves 2 dests needing
//     different words.)
//  2. cen_ws STAGED IN LDS (32KB, swizzle col4^=m&7 both sides, algebra
//     re-verified): epilogue's 32 per-wave L2 loads -> ds_read_b128;
//     R14's 32-reg prefetch pipeline deleted.
// Keeps R14: batched ff/wbv bursts, two-pass softmax, ep packed f16x2 in
// regs, transposed GEMM2 (row c, dwordx4 imm-offset stores), geometric
// batch fold (x+=4096*b; cross-batch exp -> exact 0; gate d2m<4e6),
// __launch_bounds__(256,3).

#define NN 100000
#define MM 256
#define LL 128
#define DD 64
#define NTILES (NN / 16)  // 6250, exact

typedef float f32x4 __attribute__((ext_vector_type(4)));
typedef __bf16 bf16x8 __attribute__((ext_vector_type(8)));
typedef __fp16 fp16x2 __attribute__((ext_vector_type(2)));

union U16x8 { uint4 u; bf16x8 v; unsigned short s[8]; };
union UH2 { unsigned int u; fp16x2 h; };

static __device__ __forceinline__ unsigned short f2bf(float f) {
  union { float f; unsigned int i; } t; t.f = f;
  unsigned int x = t.i;
  x += 0x7fffu + ((x >> 16) & 1u);  // round-to-nearest-even
  return (unsigned short)(x >> 16);
}

static __device__ __forceinline__ unsigned int pk_bf16(float lo, float hi) {
  unsigned int r;
  asm("v_cvt_pk_bf16_f32 %0, %1, %2" : "=v"(r) : "v"(lo), "v"(hi));
  return r;
}

// ---------------- prep: cen (bf16), W^T (bf16), centroid meta ----------------
__global__ __launch_bounds__(256) void prep_kernel(
    const int* __restrict__ cen_coords,
    const float* __restrict__ cen_feats,
    const float* __restrict__ conf,
    const float* __restrict__ W,
    const float* __restrict__ bvec,
    unsigned short* __restrict__ cen_ws,   // [256][64] bf16
    unsigned short* __restrict__ wt_ws,    // [64][128] bf16 (W transposed)
    float4* __restrict__ cmeta_ws)         // [256] {x+4096*batch, y, z, 0}
{
  int tid = threadIdx.x;
  if (blockIdx.x < 16) {
    int m = blockIdx.x * 16 + (tid >> 4);
    int c = tid & 15;
    float a0 = 0.f, a1 = 0.f, a2 = 0.f, a3 = 0.f;
    for (int l = 0; l < LL; l++) {
      float f = cen_feats[m * LL + l];
      const float* wr = W + l * DD + c;
      a0 += f * wr[0];  a1 += f * wr[16];
      a2 += f * wr[32]; a3 += f * wr[48];
    }
    float cf = conf[m];
    cen_ws[m * DD + c +  0] = f2bf(cf * (a0 + bvec[c +  0]));
    cen_ws[m * DD + c + 16] = f2bf(cf * (a1 + bvec[c + 16]));
    cen_ws[m * DD + c + 32] = f2bf(cf * (a2 + bvec[c + 32]));
    cen_ws[m * DD + c + 48] = f2bf(cf * (a3 + bvec[c + 48]));
  } else {
    for (int i = tid; i < LL * DD; i += 256) {
      int l = i >> 6, d = i & 63;
      wt_ws[d * LL + l] = f2bf(W[l * DD + d]);
    }
    {
      int4 cc = ((const int4*)cen_coords)[tid];  // {batch, x, y, z}
      float4 f;
      f.x = (float)cc.y + 4096.0f * (float)cc.x;  // batch folded into x
      f.y = (float)cc.z;
      f.z = (float)cc.w;
      f.w = 0.0f;
      cmeta_ws[tid] = f;
    }
  }
}

// ---------------- main: fused, 1 wave/tile ----------------
__global__ __launch_bounds__(256, 3) void main_kernel(
    const int4* __restrict__ clu_coords4,
    const float* __restrict__ feats,
    const float* __restrict__ bvec,
    const unsigned short* __restrict__ cen_ws,
    const unsigned short* __restrict__ wt_ws,
    const float4* __restrict__ cmeta,
    float* __restrict__ out)
{
  __shared__ __align__(16) uint4 cen_s4[2048];                // 32 KB, swizzled
  __shared__ __align__(16) float4 cmeta_s[MM];                // 4 KB
  __shared__ __align__(16) unsigned short clu_s[4][16 * 72];  // 9 KB, wave-private

  int tid = threadIdx.x;
  int wave = tid >> 6, lane = tid & 63;
  int q = lane >> 4, c = lane & 15, s = c & 7;
  int tile = blockIdx.x * 4 + wave;
  int tl = tile < NTILES ? tile : NTILES - 1;    // clamp (2 dead waves total)

  // ---- cen staging loads FIRST (8 uint4/thread, pre-swizzled gather;
  //      XOR stays inside a 128B line -> fully coalesced)
  const uint4* cg = (const uint4*)cen_ws;
  uint4 st[8];
#pragma unroll
  for (int i = 0; i < 8; i++) {
    int fl = tid + i * 256;                       // LDS slot
    int g = (fl & ~7) | ((fl ^ (fl >> 3)) & 7);   // source: col4 ^ (m&7)
    st[i] = cg[g];
  }

  // ---- per-wave bursts: feats (8x dwordx4) + W frags (16x dwordx4)
  const float4* fb = (const float4*)(feats + (size_t)(tl * 16 + c) * LL);
  float4 ff[8];
#pragma unroll
  for (int ks = 0; ks < 4; ks++) {
    ff[2 * ks]     = fb[ks * 8 + q * 2];
    ff[2 * ks + 1] = fb[ks * 8 + q * 2 + 1];
  }
  const uint4* wb = (const uint4*)wt_ws;
  uint4 wbv[16];
#pragma unroll
  for (int ks = 0; ks < 4; ks++)
#pragma unroll
    for (int nt = 0; nt < 4; nt++)
      wbv[ks * 4 + nt] = wb[(nt * 16 + c) * 16 + ks * 4 + q];

  // ---- commit staging to LDS + cmeta; one barrier before divergence
  //      (waits only the st loads' vmcnt slots; ff/wbv stay in flight)
#pragma unroll
  for (int i = 0; i < 8; i++) cen_s4[tid + i * 256] = st[i];
  cmeta_s[tid] = cmeta[tid];
  __syncthreads();
  if (tile >= NTILES) return;

  // ---- row meta + bias (hidden under GEMM1's waits)
  int4 rm = clu_coords4[tile * 16 + c];           // one row per lane
  float rx = (float)rm.y + 4096.0f * (float)rm.x; // batch folded, exact
  float ry = (float)rm.z;
  float rz = (float)rm.w;
  const float4* bv4 = (const float4*)bvec;
  float4 bb[4];
#pragma unroll
  for (int nt = 0; nt < 4; nt++) bb[nt] = bv4[nt * 4 + q];

  // ---- GEMM1 SWAPPED: acc[nt] lane (c,q) reg r = clu[i=c][d=nt*16+q*4+r]
  f32x4 acc[4] = {{0,0,0,0},{0,0,0,0},{0,0,0,0},{0,0,0,0}};
#pragma unroll
  for (int ks = 0; ks < 4; ks++) {
    float4 f0 = ff[2 * ks], f1 = ff[2 * ks + 1];
    U16x8 a;
    a.v[0] = (__bf16)f0.x; a.v[1] = (__bf16)f0.y; a.v[2] = (__bf16)f0.z; a.v[3] = (__bf16)f0.w;
    a.v[4] = (__bf16)f1.x; a.v[5] = (__bf16)f1.y; a.v[6] = (__bf16)f1.z; a.v[7] = (__bf16)f1.w;
#pragma unroll
    for (int nt = 0; nt < 4; nt++) {
      U16x8 b; b.u = wbv[ks * 4 + nt];
      acc[nt] = __builtin_amdgcn_mfma_f32_16x16x32_bf16(b.v, a.v, acc[nt], 0, 0, 0);  // SWAPPED
    }
  }
#pragma unroll
  for (int nt = 0; nt < 4; nt++) {
    acc[nt][0] += bb[nt][0]; acc[nt][1] += bb[nt][1];
    acc[nt][2] += bb[nt][2]; acc[nt][3] += bb[nt][3];
  }
  // ---- row norm: per-lane partial (16 d-values) + 2 shuffles over q-lanes
  float ns = 0.f;
#pragma unroll
  for (int nt = 0; nt < 4; nt++)
#pragma unroll
    for (int r = 0; r < 4; r++) ns += acc[nt][r] * acc[nt][r];
  ns += __shfl_xor(ns, 16);
  ns += __shfl_xor(ns, 32);
  float inv_nrm = 1.0f / fmaxf(sqrtf(ns), 1e-12f);

  // ---- normalized clu -> LDS: 4x ds_write_b64 (contiguous d per nt)
#pragma unroll
  for (int nt = 0; nt < 4; nt++) {
    uint2 w;
    w.x = pk_bf16(acc[nt][0] * inv_nrm, acc[nt][1] * inv_nrm);
    w.y = pk_bf16(acc[nt][2] * inv_nrm, acc[nt][3] * inv_nrm);
    *(uint2*)&clu_s[wave][c * 72 + nt * 16 + q * 4] = w;  // 8B-aligned
  }

  // wave-private LDS transpose: DS pipe is in-order per wave, no barrier
  __builtin_amdgcn_sched_barrier(0);

  // ---- clu frags (B-operand of the swapped GEMM2): row c, k-slice q
  //      (read path byte-identical to R14)
  const uint4* cb = (const uint4*)(clu_s[wave]);
  U16x8 a0, a1;
  a0.u = cb[c * 9 + q];       // k = q*8 .. q*8+7
  a1.u = cb[c * 9 + 4 + q];   // k = 32+q*8 ..

  // ---- pass 1: d^2 min for (row c, cols mt*16+q*4+r) — per-lane scalar
  float d2m = 1e30f;
#pragma unroll
  for (int mt = 0; mt < 16; mt++) {
#pragma unroll
    for (int r = 0; r < 4; r++) {
      float4 cm = cmeta_s[mt * 16 + q * 4 + r];
      float dx = rx - cm.x, dy = ry - cm.y, dz = rz - cm.z;
      d2m = fminf(d2m, dx * dx + dy * dy + dz * dz);
    }
  }
  d2m = fminf(d2m, __shfl_xor(d2m, 16));
  d2m = fminf(d2m, __shfl_xor(d2m, 32));
  float dmv = fmaxf(sqrtf(d2m), 0.1f);  // softmax reference (row min dist)

  // ---- pass 2: e = exp(dmin - d) once; pack f16x2 along r; row sum
  uint2 ep[16];
  float rsum = 0.f;
#pragma unroll
  for (int mt = 0; mt < 16; mt++) {
    float e[4];
#pragma unroll
    for (int r = 0; r < 4; r++) {
      float4 cm = cmeta_s[mt * 16 + q * 4 + r];
      float dx = rx - cm.x, dy = ry - cm.y, dz = rz - cm.z;
      float d = fmaxf(sqrtf(dx * dx + dy * dy + dz * dz), 0.1f);
      e[r] = __expf(dmv - d);  // <= 1; cross-batch -> exact 0
      rsum += e[r];
    }
    UH2 p0, p1;
    p0.h = __builtin_amdgcn_cvt_pkrtz(e[0], e[1]);
    p1.h = __builtin_amdgcn_cvt_pkrtz(e[2], e[3]);
    ep[mt].x = p0.u;
    ep[mt].y = p1.u;
  }
  rsum += __shfl_xor(rsum, 16);
  rsum += __shfl_xor(rsum, 32);
  // d2m >= 4e6 <=> no same-batch centroid -> exact-zero row
  float sc = (d2m < 4.0e6f) ? 1.0f / rsum : 0.f;

  // ---- epilogue: swapped GEMM2; cen A-frags from swizzled LDS
  //      (slot = (mt*16+c)*8 + (col4 ^ (c&7)), col4 = q / q+4)
  float4* ob4 = (float4*)(out + (size_t)(tile * 16 + c) * MM) + q;
  int i0 = c * 8 + (q ^ s);
  int i1 = c * 8 + ((q + 4) ^ s);
#pragma unroll
  for (int mt = 0; mt < 16; mt++) {
    U16x8 b0, b1;
    b0.u = cen_s4[mt * 128 + i0];
    b1.u = cen_s4[mt * 128 + i1];
    f32x4 dacc = {0, 0, 0, 0};
    dacc = __builtin_amdgcn_mfma_f32_16x16x32_bf16(b0.v, a0.v, dacc, 0, 0, 0);
    dacc = __builtin_amdgcn_mfma_f32_16x16x32_bf16(b1.v, a1.v, dacc, 0, 0, 0);
    UH2 p0, p1; p0.u = ep[mt].x; p1.u = ep[mt].y;
    float4 v;
    v.x = dacc[0] * ((float)p0.h[0] * sc);
    v.y = dacc[1] * ((float)p0.h[1] * sc);
    v.z = dacc[2] * ((float)p1.h[0] * sc);
    v.w = dacc[3] * ((float)p1.h[1] * sc);
    ob4[mt * 4] = v;   // imm offset mt*64B, one base per lane
  }
}

extern "C" void kernel_launch(void* const* d_in, const int* in_sizes, int n_in,
                              void* d_out, int out_size, void* d_ws, size_t ws_size,
                              hipStream_t stream) {
  const int* clu_coords = (const int*)d_in[0];
  const int* cen_coords = (const int*)d_in[1];
  const float* clu_feats = (const float*)d_in[2];
  const float* cen_feats = (const float*)d_in[3];
  const float* conf      = (const float*)d_in[4];
  const float* W         = (const float*)d_in[5];
  const float* bvec      = (const float*)d_in[6];
  float* out = (float*)d_out;

  char* ws = (char*)d_ws;
  unsigned short* cen_ws = (unsigned short*)ws;              // 32768 B
  unsigned short* wt_ws  = (unsigned short*)(ws + 32768);    // 16384 B
  float4* cmeta_ws       = (float4*)(ws + 32768 + 16384);    // 4096 B

  prep_kernel<<<17, 256, 0, stream>>>(cen_coords, cen_feats, conf, W, bvec,
                                      cen_ws, wt_ws, cmeta_ws);
  main_kernel<<<(NTILES + 3) / 4, 256, 0, stream>>>(
      (const int4*)clu_coords, clu_feats, bvec, cen_ws, wt_ws, cmeta_ws, out);
}